// Round 1
// baseline (241.621 us; speedup 1.0000x reference)
//
#include <hip/hip_runtime.h>

// Problem constants (fixed by the reference)
constexpr int C = 16;       // channels
constexpr int E = 65536;    // events per channel
constexpr int K = 5;        // kernel size
constexpr int O = 64;       // out channels
constexpr int R = 98;       // ref size
constexpr int B = 256;      // batch
constexpr int RB = R * B;   // 25088 scatter rows
constexpr int NEV = C * E;  // 1,048,576 events

// ---------------------------------------------------------------------------
// Kernel 1a: scatter-add into workspace conv[RB][O] (lanes contiguous in O)
// ---------------------------------------------------------------------------
__global__ void scatter_ws_kernel(const float* __restrict__ pseudo,
                                  const float* __restrict__ y,
                                  const float* __restrict__ weight,   // [K][C][O]
                                  const int*   __restrict__ ref_idx,  // [C*E]
                                  float*       __restrict__ conv)     // [RB][O]
{
    __shared__ float sw[K * C * O];  // 5120 floats = 20 KB
    for (int i = threadIdx.x; i < K * C * O; i += blockDim.x)
        sw[i] = weight[i];
    __syncthreads();

    const int lane   = threadIdx.x & 63;
    const int wave   = (blockIdx.x * blockDim.x + threadIdx.x) >> 6;
    const int nwaves = (gridDim.x * blockDim.x) >> 6;

    for (int ev = wave; ev < NEV; ev += nwaves) {
        const int   c    = ev >> 16;           // E = 65536
        const float p    = pseudo[ev];
        const float yy   = y[ev];
        const int   ridx = ref_idx[ev];

        const float v    = p * (float)(K - 1);
        const float bot  = floorf(v);
        const float frac = v - bot;
        int i0 = (int)bot;
        int i1 = i0 + 1;
        if (i1 == K) i1 = 0;   // wrap (only matters when frac == 0)

        const float w0 = sw[(i0 * C + c) * O + lane];
        const float w1 = sw[(i1 * C + c) * O + lane];
        const float outv = yy * ((1.0f - frac) * w0 + frac * w1);

        atomicAdd(&conv[ridx * O + lane], outv);
    }
}

// ---------------------------------------------------------------------------
// Kernel 2: out[b][o][r] = conv[b*R + r][o] + bias[o]
// ---------------------------------------------------------------------------
__global__ void finalize_kernel(const float* __restrict__ conv,
                                const float* __restrict__ bias,
                                float*       __restrict__ out)
{
    const int idx = blockIdx.x * blockDim.x + threadIdx.x;
    if (idx >= B * O * R) return;
    const int r = idx % R;
    const int t = idx / R;
    const int o = t % O;
    const int b = t / O;
    out[idx] = conv[(b * R + r) * O + o] + bias[o];
}

// ---------------------------------------------------------------------------
// Fallback path (if ws too small): init out with bias, scatter directly
// ---------------------------------------------------------------------------
__global__ void init_out_kernel(const float* __restrict__ bias,
                                float*       __restrict__ out)
{
    const int idx = blockIdx.x * blockDim.x + threadIdx.x;
    if (idx >= B * O * R) return;
    const int o = (idx / R) % O;
    out[idx] = bias[o];
}

__global__ void scatter_direct_kernel(const float* __restrict__ pseudo,
                                      const float* __restrict__ y,
                                      const float* __restrict__ weight,
                                      const int*   __restrict__ ref_idx,
                                      float*       __restrict__ out)   // [B][O][R]
{
    __shared__ float sw[K * C * O];
    for (int i = threadIdx.x; i < K * C * O; i += blockDim.x)
        sw[i] = weight[i];
    __syncthreads();

    const int lane   = threadIdx.x & 63;
    const int wave   = (blockIdx.x * blockDim.x + threadIdx.x) >> 6;
    const int nwaves = (gridDim.x * blockDim.x) >> 6;

    for (int ev = wave; ev < NEV; ev += nwaves) {
        const int   c    = ev >> 16;
        const float p    = pseudo[ev];
        const float yy   = y[ev];
        const int   ridx = ref_idx[ev];
        const int   b    = ridx / R;
        const int   r    = ridx - b * R;

        const float v    = p * (float)(K - 1);
        const float bot  = floorf(v);
        const float frac = v - bot;
        int i0 = (int)bot;
        int i1 = i0 + 1;
        if (i1 == K) i1 = 0;

        const float w0 = sw[(i0 * C + c) * O + lane];
        const float w1 = sw[(i1 * C + c) * O + lane];
        const float outv = yy * ((1.0f - frac) * w0 + frac * w1);

        atomicAdd(&out[(b * O + lane) * R + r], outv);
    }
}

// ---------------------------------------------------------------------------
extern "C" void kernel_launch(void* const* d_in, const int* in_sizes, int n_in,
                              void* d_out, int out_size, void* d_ws, size_t ws_size,
                              hipStream_t stream)
{
    const float* pseudo  = (const float*)d_in[0];  // [C,E,1]
    const float* y       = (const float*)d_in[1];  // [C,E,1]
    const float* weight  = (const float*)d_in[2];  // [K,C,O]
    const float* bias    = (const float*)d_in[3];  // [O]
    const int*   ref_idx = (const int*)d_in[4];    // [C,E]
    // d_in[5] = ref_deg (unused), d_in[6] = batch_size (constant 256)

    float* out = (float*)d_out;

    const size_t conv_bytes = (size_t)RB * O * sizeof(float);

    const int scatter_blocks = 4096;   // 16384 waves, 64 events each
    const int scatter_threads = 256;
    const int fin_threads = 256;
    const int fin_blocks = (B * O * R + fin_threads - 1) / fin_threads;

    if (ws_size >= conv_bytes) {
        float* conv = (float*)d_ws;
        hipMemsetAsync(conv, 0, conv_bytes, stream);
        scatter_ws_kernel<<<scatter_blocks, scatter_threads, 0, stream>>>(
            pseudo, y, weight, ref_idx, conv);
        finalize_kernel<<<fin_blocks, fin_threads, 0, stream>>>(conv, bias, out);
    } else {
        init_out_kernel<<<fin_blocks, fin_threads, 0, stream>>>(bias, out);
        scatter_direct_kernel<<<scatter_blocks, scatter_threads, 0, stream>>>(
            pseudo, y, weight, ref_idx, out);
    }
}

// Round 2
// 133.578 us; speedup vs baseline: 1.8088x; 1.8088x over previous
//
#include <hip/hip_runtime.h>

// Problem constants (fixed by the reference)
constexpr int C = 16;       // channels
constexpr int E = 65536;    // events per channel
constexpr int K = 5;        // kernel size
constexpr int O = 64;       // out channels
constexpr int R = 98;       // ref size
constexpr int B = 256;      // batch
constexpr int RB = R * B;   // 25088 scatter rows
constexpr int NEV = C * E;  // 1,048,576 events
constexpr int KC = K * C;   // 80 basis slots per row

// ---------------------------------------------------------------------------
// Phase 1: scatter scalar basis coefficients into S[RB][KC]
//   S[ridx][i0*C + c] += y*(1-frac);  S[ridx][i1*C + c] += y*frac
// 2 atomics per event (vs 64 in the old formulation).
// ---------------------------------------------------------------------------
__global__ void accum_S_kernel(const float* __restrict__ pseudo,
                               const float* __restrict__ y,
                               const int*   __restrict__ ref_idx,
                               float*       __restrict__ S)      // [RB][KC]
{
    const int stride = gridDim.x * blockDim.x;
    for (int ev = blockIdx.x * blockDim.x + threadIdx.x; ev < NEV; ev += stride) {
        const int   c    = ev >> 16;            // E = 65536
        const float p    = pseudo[ev];
        const float yy   = y[ev];
        const int   ridx = ref_idx[ev];

        const float v    = p * (float)(K - 1);
        const float bot  = floorf(v);
        const float frac = v - bot;
        int i0 = (int)bot;
        int i1 = i0 + 1;
        if (i1 == K) i1 = 0;                    // wrap only when frac == 0

        float* Srow = S + (size_t)ridx * KC;
        atomicAdd(&Srow[i0 * C + c], yy * (1.0f - frac));
        atomicAdd(&Srow[i1 * C + c], yy * frac);
    }
}

// ---------------------------------------------------------------------------
// Phase 2: out[b][o][r] = sum_kc S[b*R+r][kc] * w[kc][o] + bias[o]
// One block per b. S_b and w staged in LDS; register-tiled over r.
// Thread t: o = t>>2 (0..63), rg = t&3; handles rows r = rg + 4*j.
// ---------------------------------------------------------------------------
constexpr int SPAD = 81;   // pad row stride to break bank aliasing
constexpr int NRJ  = 25;   // ceil(98/4)

__global__ void __launch_bounds__(256)
gemm_out_kernel(const float* __restrict__ S,
                const float* __restrict__ weight,   // [K][C][O] == [KC][O]
                const float* __restrict__ bias,
                float*       __restrict__ out)      // [B][O][R]
{
    __shared__ float s_S[R * SPAD];    // 98*81*4 = 31752 B
    __shared__ float s_w[KC * O];      // 80*64*4 = 20480 B

    const int b = blockIdx.x;
    const float* Sb = S + (size_t)b * R * KC;

    for (int i = threadIdx.x; i < R * KC; i += 256) {
        const int r = i / KC, kc = i - r * KC;
        s_S[r * SPAD + kc] = Sb[i];
    }
    for (int i = threadIdx.x; i < KC * O; i += 256)
        s_w[i] = weight[i];
    __syncthreads();

    const int o  = threadIdx.x >> 2;
    const int rg = threadIdx.x & 3;

    float acc[NRJ];
#pragma unroll
    for (int j = 0; j < NRJ; ++j) acc[j] = 0.0f;

    for (int kc = 0; kc < KC; ++kc) {
        const float wv = s_w[kc * O + o];
#pragma unroll
        for (int j = 0; j < NRJ; ++j) {
            const int r = rg + 4 * j;
            if (r < R) acc[j] += wv * s_S[r * SPAD + kc];
        }
    }

    const float bs = bias[o];
    float* orow = out + ((size_t)b * O + o) * R;
#pragma unroll
    for (int j = 0; j < NRJ; ++j) {
        const int r = rg + 4 * j;
        if (r < R) orow[r] = acc[j] + bs;
    }
}

// ---------------------------------------------------------------------------
// Fallback path (ws too small): init out with bias, scatter directly (old way)
// ---------------------------------------------------------------------------
__global__ void init_out_kernel(const float* __restrict__ bias,
                                float*       __restrict__ out)
{
    const int idx = blockIdx.x * blockDim.x + threadIdx.x;
    if (idx >= B * O * R) return;
    const int o = (idx / R) % O;
    out[idx] = bias[o];
}

__global__ void scatter_direct_kernel(const float* __restrict__ pseudo,
                                      const float* __restrict__ y,
                                      const float* __restrict__ weight,
                                      const int*   __restrict__ ref_idx,
                                      float*       __restrict__ out)   // [B][O][R]
{
    __shared__ float sw[KC * O];
    for (int i = threadIdx.x; i < KC * O; i += blockDim.x)
        sw[i] = weight[i];
    __syncthreads();

    const int lane   = threadIdx.x & 63;
    const int wave   = (blockIdx.x * blockDim.x + threadIdx.x) >> 6;
    const int nwaves = (gridDim.x * blockDim.x) >> 6;

    for (int ev = wave; ev < NEV; ev += nwaves) {
        const int   c    = ev >> 16;
        const float p    = pseudo[ev];
        const float yy   = y[ev];
        const int   ridx = ref_idx[ev];
        const int   b    = ridx / R;
        const int   r    = ridx - b * R;

        const float v    = p * (float)(K - 1);
        const float bot  = floorf(v);
        const float frac = v - bot;
        int i0 = (int)bot;
        int i1 = i0 + 1;
        if (i1 == K) i1 = 0;

        const float w0 = sw[(i0 * C + c) * O + lane];
        const float w1 = sw[(i1 * C + c) * O + lane];
        atomicAdd(&out[((size_t)b * O + lane) * R + r],
                  yy * ((1.0f - frac) * w0 + frac * w1));
    }
}

// ---------------------------------------------------------------------------
extern "C" void kernel_launch(void* const* d_in, const int* in_sizes, int n_in,
                              void* d_out, int out_size, void* d_ws, size_t ws_size,
                              hipStream_t stream)
{
    const float* pseudo  = (const float*)d_in[0];  // [C,E,1]
    const float* y       = (const float*)d_in[1];  // [C,E,1]
    const float* weight  = (const float*)d_in[2];  // [K,C,O]
    const float* bias    = (const float*)d_in[3];  // [O]
    const int*   ref_idx = (const int*)d_in[4];    // [C,E]
    // d_in[5] = ref_deg (unused), d_in[6] = batch_size (constant 256)

    float* out = (float*)d_out;

    const size_t S_bytes = (size_t)RB * KC * sizeof(float);   // ~8 MB

    if (ws_size >= S_bytes) {
        float* S = (float*)d_ws;
        hipMemsetAsync(S, 0, S_bytes, stream);
        accum_S_kernel<<<2048, 256, 0, stream>>>(pseudo, y, ref_idx, S);
        gemm_out_kernel<<<B, 256, 0, stream>>>(S, weight, bias, out);
    } else {
        const int fin_threads = 256;
        const int fin_blocks = (B * O * R + fin_threads - 1) / fin_threads;
        init_out_kernel<<<fin_blocks, fin_threads, 0, stream>>>(bias, out);
        scatter_direct_kernel<<<4096, 256, 0, stream>>>(
            pseudo, y, weight, ref_idx, out);
    }
}

// Round 3
// 94.187 us; speedup vs baseline: 2.5653x; 1.4182x over previous
//
#include <hip/hip_runtime.h>

// Problem constants (fixed by the reference)
constexpr int C = 16;       // channels
constexpr int E = 65536;    // events per channel
constexpr int K = 5;        // kernel size
constexpr int O = 64;       // out channels
constexpr int R = 98;       // ref size
constexpr int B = 256;      // batch
constexpr int RB = R * B;   // 25088 scatter rows
constexpr int NEV = C * E;  // 1,048,576 events
constexpr int KC = K * C;   // 80 basis slots per row

// ---------------------------------------------------------------------------
// Phase 1 (v3): 8-lane cooperative scatter into S8[RB][C][8].
// Lanes l=0..7 share one event; only l==i0 and l==i0+1 carry nonzero values,
// both inside ONE 32B sector -> single merged sector-RMW per event.
// ---------------------------------------------------------------------------
__global__ void accum_S8_kernel(const float* __restrict__ pseudo,
                                const float* __restrict__ y,
                                const int*   __restrict__ ref_idx,
                                float*       __restrict__ S8)   // [RB][C][8]
{
    const int tid  = blockIdx.x * blockDim.x + threadIdx.x;
    const int l    = tid & 7;        // lane within 8-group
    const int grp  = tid >> 3;       // global group id
    const int ngrp = (gridDim.x * blockDim.x) >> 3;

    for (int ev = grp; ev < NEV; ev += ngrp) {
        const int   c    = ev >> 16;            // E = 65536
        const float p    = pseudo[ev];
        const float yy   = y[ev];
        const int   ridx = ref_idx[ev];

        const float v    = p * (float)(K - 1);
        const float bot  = floorf(v);
        const float frac = v - bot;
        const int   i0   = (int)bot;            // 0..3 since p in [0,1)

        float val = 0.0f;
        if (l == i0)     val = yy * (1.0f - frac);
        if (l == i0 + 1) val = yy * frac;       // i0+1 <= 4, never wraps

        if (val != 0.0f)
            atomicAdd(&S8[(((size_t)ridx * C) + c) * 8 + l], val);
    }
}

// ---------------------------------------------------------------------------
// Phase 2 (v2): out[b][o][r] = sum_kc S[b*R+r][kc] * w[kc][o] + bias[o]
// 512 blocks: (b, o-half of 32). s_S padded to 84 for float4 reads.
// Thread t: oo = t>>3 (0..31), rg = t&7; rows r = rg + 8*j.
// ---------------------------------------------------------------------------
constexpr int SPAD = 84;   // 80 rounded up to x4, odd multiple of 4 -> bank spread
constexpr int NRJ  = 13;   // ceil(98/8)

__global__ void __launch_bounds__(256)
gemm_out_kernel(const float* __restrict__ S8,      // [RB][C][8]
                const float* __restrict__ weight,  // [KC][O]
                const float* __restrict__ bias,
                float*       __restrict__ out)     // [B][O][R]
{
    __shared__ __align__(16) float s_S[R * SPAD];  // 98*84*4 = 32928 B
    __shared__ float s_w[KC * 32];                 // 10240 B

    const int b    = blockIdx.x >> 1;
    const int half = blockIdx.x & 1;
    const int o0   = half * 32;

    const float* S8b = S8 + (size_t)b * R * C * 8;

    // load S8b -> s_S with layout change: s_S[r][i*16+c] = S8b[r][c][i]
    for (int idx = threadIdx.x; idx < R * C * 8; idx += 256) {
        const int r   = idx >> 7;          // /128
        const int rem = idx & 127;
        const int c   = rem >> 3;
        const int i   = rem & 7;
        if (i < K) s_S[r * SPAD + i * C + c] = S8b[idx];
    }
    // load this half's weights: s_w[kc*32 + (o-o0)]
    for (int idx = threadIdx.x; idx < KC * 32; idx += 256) {
        const int kc = idx >> 5;
        const int oo = idx & 31;
        s_w[idx] = weight[kc * O + o0 + oo];
    }
    __syncthreads();

    const int oo = threadIdx.x >> 3;   // 0..31
    const int rg = threadIdx.x & 7;    // 0..7

    float acc[NRJ];
#pragma unroll
    for (int j = 0; j < NRJ; ++j) acc[j] = 0.0f;

    for (int k4 = 0; k4 < KC / 4; ++k4) {
        const float w0 = s_w[(4 * k4 + 0) * 32 + oo];
        const float w1 = s_w[(4 * k4 + 1) * 32 + oo];
        const float w2 = s_w[(4 * k4 + 2) * 32 + oo];
        const float w3 = s_w[(4 * k4 + 3) * 32 + oo];
#pragma unroll
        for (int j = 0; j < NRJ; ++j) {
            const int r = rg + 8 * j;
            if (r < R) {
                const float4 sv = *(const float4*)&s_S[r * SPAD + 4 * k4];
                acc[j] += w0 * sv.x + w1 * sv.y + w2 * sv.z + w3 * sv.w;
            }
        }
    }

    const int o = o0 + oo;
    const float bs = bias[o];
    float* orow = out + ((size_t)b * O + o) * R;
#pragma unroll
    for (int j = 0; j < NRJ; ++j) {
        const int r = rg + 8 * j;
        if (r < R) orow[r] = acc[j] + bs;
    }
}

// ---------------------------------------------------------------------------
// Mid fallback (ws in [8MB, 12.85MB)): round-2 path
// ---------------------------------------------------------------------------
__global__ void accum_S_kernel(const float* __restrict__ pseudo,
                               const float* __restrict__ y,
                               const int*   __restrict__ ref_idx,
                               float*       __restrict__ S)      // [RB][KC]
{
    const int stride = gridDim.x * blockDim.x;
    for (int ev = blockIdx.x * blockDim.x + threadIdx.x; ev < NEV; ev += stride) {
        const int   c    = ev >> 16;
        const float p    = pseudo[ev];
        const float yy   = y[ev];
        const int   ridx = ref_idx[ev];

        const float v    = p * (float)(K - 1);
        const float bot  = floorf(v);
        const float frac = v - bot;
        int i0 = (int)bot;
        int i1 = i0 + 1;
        if (i1 == K) i1 = 0;

        float* Srow = S + (size_t)ridx * KC;
        atomicAdd(&Srow[i0 * C + c], yy * (1.0f - frac));
        atomicAdd(&Srow[i1 * C + c], yy * frac);
    }
}

constexpr int SPAD2 = 81;
constexpr int NRJ2  = 25;

__global__ void __launch_bounds__(256)
gemm_out_kernel_flat(const float* __restrict__ S,
                     const float* __restrict__ weight,
                     const float* __restrict__ bias,
                     float*       __restrict__ out)
{
    __shared__ float s_S[R * SPAD2];
    __shared__ float s_w[KC * O];

    const int b = blockIdx.x;
    const float* Sb = S + (size_t)b * R * KC;

    for (int i = threadIdx.x; i < R * KC; i += 256) {
        const int r = i / KC, kc = i - r * KC;
        s_S[r * SPAD2 + kc] = Sb[i];
    }
    for (int i = threadIdx.x; i < KC * O; i += 256)
        s_w[i] = weight[i];
    __syncthreads();

    const int o  = threadIdx.x >> 2;
    const int rg = threadIdx.x & 3;

    float acc[NRJ2];
#pragma unroll
    for (int j = 0; j < NRJ2; ++j) acc[j] = 0.0f;

    for (int kc = 0; kc < KC; ++kc) {
        const float wv = s_w[kc * O + o];
#pragma unroll
        for (int j = 0; j < NRJ2; ++j) {
            const int r = rg + 4 * j;
            if (r < R) acc[j] += wv * s_S[r * SPAD2 + kc];
        }
    }

    const float bs = bias[o];
    float* orow = out + ((size_t)b * O + o) * R;
#pragma unroll
    for (int j = 0; j < NRJ2; ++j) {
        const int r = rg + 4 * j;
        if (r < R) orow[r] = acc[j] + bs;
    }
}

// ---------------------------------------------------------------------------
// Last fallback: direct scatter into out
// ---------------------------------------------------------------------------
__global__ void init_out_kernel(const float* __restrict__ bias,
                                float*       __restrict__ out)
{
    const int idx = blockIdx.x * blockDim.x + threadIdx.x;
    if (idx >= B * O * R) return;
    const int o = (idx / R) % O;
    out[idx] = bias[o];
}

__global__ void scatter_direct_kernel(const float* __restrict__ pseudo,
                                      const float* __restrict__ y,
                                      const float* __restrict__ weight,
                                      const int*   __restrict__ ref_idx,
                                      float*       __restrict__ out)
{
    __shared__ float sw[KC * O];
    for (int i = threadIdx.x; i < KC * O; i += blockDim.x)
        sw[i] = weight[i];
    __syncthreads();

    const int lane   = threadIdx.x & 63;
    const int wave   = (blockIdx.x * blockDim.x + threadIdx.x) >> 6;
    const int nwaves = (gridDim.x * blockDim.x) >> 6;

    for (int ev = wave; ev < NEV; ev += nwaves) {
        const int   c    = ev >> 16;
        const float p    = pseudo[ev];
        const float yy   = y[ev];
        const int   ridx = ref_idx[ev];
        const int   b    = ridx / R;
        const int   r    = ridx - b * R;

        const float v    = p * (float)(K - 1);
        const float bot  = floorf(v);
        const float frac = v - bot;
        int i0 = (int)bot;
        int i1 = i0 + 1;
        if (i1 == K) i1 = 0;

        const float w0 = sw[(i0 * C + c) * O + lane];
        const float w1 = sw[(i1 * C + c) * O + lane];
        atomicAdd(&out[((size_t)b * O + lane) * R + r],
                  yy * ((1.0f - frac) * w0 + frac * w1));
    }
}

// ---------------------------------------------------------------------------
extern "C" void kernel_launch(void* const* d_in, const int* in_sizes, int n_in,
                              void* d_out, int out_size, void* d_ws, size_t ws_size,
                              hipStream_t stream)
{
    const float* pseudo  = (const float*)d_in[0];  // [C,E,1]
    const float* y       = (const float*)d_in[1];  // [C,E,1]
    const float* weight  = (const float*)d_in[2];  // [K,C,O]
    const float* bias    = (const float*)d_in[3];  // [O]
    const int*   ref_idx = (const int*)d_in[4];    // [C,E]

    float* out = (float*)d_out;

    const size_t S8_bytes = (size_t)RB * C * 8 * sizeof(float);  // 12.85 MB
    const size_t S_bytes  = (size_t)RB * KC * sizeof(float);     // ~8 MB

    if (ws_size >= S8_bytes) {
        float* S8 = (float*)d_ws;
        hipMemsetAsync(S8, 0, S8_bytes, stream);
        accum_S8_kernel<<<4096, 256, 0, stream>>>(pseudo, y, ref_idx, S8);
        gemm_out_kernel<<<2 * B, 256, 0, stream>>>(S8, weight, bias, out);
    } else if (ws_size >= S_bytes) {
        float* S = (float*)d_ws;
        hipMemsetAsync(S, 0, S_bytes, stream);
        accum_S_kernel<<<2048, 256, 0, stream>>>(pseudo, y, ref_idx, S);
        gemm_out_kernel_flat<<<B, 256, 0, stream>>>(S, weight, bias, out);
    } else {
        const int fin_threads = 256;
        const int fin_blocks = (B * O * R + fin_threads - 1) / fin_threads;
        init_out_kernel<<<fin_blocks, fin_threads, 0, stream>>>(bias, out);
        scatter_direct_kernel<<<4096, 256, 0, stream>>>(
            pseudo, y, weight, ref_idx, out);
    }
}

// Round 4
// 91.025 us; speedup vs baseline: 2.6544x; 1.0347x over previous
//
#include <hip/hip_runtime.h>

// Problem constants (fixed by the reference)
constexpr int C = 16;       // channels
constexpr int E = 65536;    // events per channel
constexpr int K = 5;        // kernel size
constexpr int O = 64;       // out channels
constexpr int R = 98;       // ref size
constexpr int B = 256;      // batch
constexpr int RB = R * B;   // 25088 scatter rows
constexpr int NEV = C * E;  // 1,048,576 events
constexpr int KC = K * C;   // 80 basis slots per row

// ---------------------------------------------------------------------------
// Phase 1 (v4): 2-lane cooperative scatter into S8[RB][C][8].
// Lane pair (l=0,1) shares one event; lane l adds into slot i0+l. Both lanes
// land in ONE 32B sector -> one merged sector-RMW per event, and every atomic
// wave-instruction now carries 64 active lanes = 32 events (4x fewer
// instructions than the 8-lane version).
// ---------------------------------------------------------------------------
__global__ void accum_S8_kernel(const float* __restrict__ pseudo,
                                const float* __restrict__ y,
                                const int*   __restrict__ ref_idx,
                                float*       __restrict__ S8)   // [RB][C][8]
{
    const int tid  = blockIdx.x * blockDim.x + threadIdx.x;
    const int l    = tid & 1;        // lane within pair
    const int grp  = tid >> 1;       // global event-group id
    const int ngrp = (gridDim.x * blockDim.x) >> 1;

    for (int ev = grp; ev < NEV; ev += ngrp) {
        const int   c    = ev >> 16;            // E = 65536
        const float p    = pseudo[ev];
        const float yy   = y[ev];
        const int   ridx = ref_idx[ev];

        const float v    = p * (float)(K - 1);
        const float bot  = floorf(v);
        const float frac = v - bot;
        const int   i0   = (int)bot;            // 0..3 since p in [0,1)

        // l==0 -> slot i0 gets y*(1-frac); l==1 -> slot i0+1 gets y*frac.
        // (frac==0 wrap case in the reference adds 0 -> equivalent.)
        const float val = l ? yy * frac : yy * (1.0f - frac);
        atomicAdd(&S8[(((size_t)ridx * C) + c) * 8 + i0 + l], val);
    }
}

// ---------------------------------------------------------------------------
// Phase 2 (v3): out[b][o][r] = sum_kc S[b*R+r][kc] * w[kc][o] + bias[o]
// 256 blocks (one per b). Each thread covers TWO o values (oo, oo+32) per
// s_S float4 read -> half the LDS b128 traffic of the 2-half version.
// Weights transposed in LDS: s_w[o][kc], read as float4.
// ---------------------------------------------------------------------------
constexpr int SPAD = 84;   // row stride: mult of 4 (b128 align), 84%32=20 -> banks spread
constexpr int WPAD = 84;
constexpr int NRJ  = 13;   // ceil(98/8)

__global__ void __launch_bounds__(256)
gemm_out_kernel(const float* __restrict__ S8,      // [RB][C][8]
                const float* __restrict__ weight,  // [KC][O]
                const float* __restrict__ bias,
                float*       __restrict__ out)     // [B][O][R]
{
    __shared__ __align__(16) float s_S[R * SPAD];  // 98*84*4 = 32928 B
    __shared__ __align__(16) float s_w[O * WPAD];  // 64*84*4 = 21504 B

    const int b = blockIdx.x;
    const float* S8b = S8 + (size_t)b * R * C * 8;

    // s_S[r][i*16+c] = S8b[r][c][i]
    for (int idx = threadIdx.x; idx < R * C * 8; idx += 256) {
        const int r   = idx >> 7;          // /128
        const int rem = idx & 127;
        const int c   = rem >> 3;
        const int i   = rem & 7;
        if (i < K) s_S[r * SPAD + i * C + c] = S8b[idx];
    }
    // s_w[o][kc] = weight[kc][o]  (transpose)
    for (int idx = threadIdx.x; idx < KC * O; idx += 256) {
        const int kc = idx >> 6;
        const int o  = idx & 63;
        s_w[o * WPAD + kc] = weight[idx];
    }
    __syncthreads();

    const int oo = threadIdx.x >> 3;   // 0..31
    const int rg = threadIdx.x & 7;    // 0..7

    float accL[NRJ], accH[NRJ];
#pragma unroll
    for (int j = 0; j < NRJ; ++j) { accL[j] = 0.0f; accH[j] = 0.0f; }

    for (int k4 = 0; k4 < KC / 4; ++k4) {
        const float4 wl = *(const float4*)&s_w[oo * WPAD + 4 * k4];
        const float4 wh = *(const float4*)&s_w[(oo + 32) * WPAD + 4 * k4];
#pragma unroll
        for (int j = 0; j < NRJ; ++j) {
            const int r = rg + 8 * j;
            if (r < R) {
                const float4 sv = *(const float4*)&s_S[r * SPAD + 4 * k4];
                accL[j] += wl.x * sv.x + wl.y * sv.y + wl.z * sv.z + wl.w * sv.w;
                accH[j] += wh.x * sv.x + wh.y * sv.y + wh.z * sv.z + wh.w * sv.w;
            }
        }
    }

    const float bL = bias[oo];
    const float bH = bias[oo + 32];
    float* orowL = out + ((size_t)b * O + oo) * R;
    float* orowH = out + ((size_t)b * O + oo + 32) * R;
#pragma unroll
    for (int j = 0; j < NRJ; ++j) {
        const int r = rg + 8 * j;
        if (r < R) {
            orowL[r] = accL[j] + bL;
            orowH[r] = accH[j] + bH;
        }
    }
}

// ---------------------------------------------------------------------------
// Mid fallback (ws in [8MB, 12.85MB)): round-2 path
// ---------------------------------------------------------------------------
__global__ void accum_S_kernel(const float* __restrict__ pseudo,
                               const float* __restrict__ y,
                               const int*   __restrict__ ref_idx,
                               float*       __restrict__ S)      // [RB][KC]
{
    const int stride = gridDim.x * blockDim.x;
    for (int ev = blockIdx.x * blockDim.x + threadIdx.x; ev < NEV; ev += stride) {
        const int   c    = ev >> 16;
        const float p    = pseudo[ev];
        const float yy   = y[ev];
        const int   ridx = ref_idx[ev];

        const float v    = p * (float)(K - 1);
        const float bot  = floorf(v);
        const float frac = v - bot;
        int i0 = (int)bot;
        int i1 = i0 + 1;
        if (i1 == K) i1 = 0;

        float* Srow = S + (size_t)ridx * KC;
        atomicAdd(&Srow[i0 * C + c], yy * (1.0f - frac));
        atomicAdd(&Srow[i1 * C + c], yy * frac);
    }
}

constexpr int SPAD2 = 81;
constexpr int NRJ2  = 25;

__global__ void __launch_bounds__(256)
gemm_out_kernel_flat(const float* __restrict__ S,
                     const float* __restrict__ weight,
                     const float* __restrict__ bias,
                     float*       __restrict__ out)
{
    __shared__ float s_S[R * SPAD2];
    __shared__ float s_w[KC * O];

    const int b = blockIdx.x;
    const float* Sb = S + (size_t)b * R * KC;

    for (int i = threadIdx.x; i < R * KC; i += 256) {
        const int r = i / KC, kc = i - r * KC;
        s_S[r * SPAD2 + kc] = Sb[i];
    }
    for (int i = threadIdx.x; i < KC * O; i += 256)
        s_w[i] = weight[i];
    __syncthreads();

    const int o  = threadIdx.x >> 2;
    const int rg = threadIdx.x & 3;

    float acc[NRJ2];
#pragma unroll
    for (int j = 0; j < NRJ2; ++j) acc[j] = 0.0f;

    for (int kc = 0; kc < KC; ++kc) {
        const float wv = s_w[kc * O + o];
#pragma unroll
        for (int j = 0; j < NRJ2; ++j) {
            const int r = rg + 4 * j;
            if (r < R) acc[j] += wv * s_S[r * SPAD2 + kc];
        }
    }

    const float bs = bias[o];
    float* orow = out + ((size_t)b * O + o) * R;
#pragma unroll
    for (int j = 0; j < NRJ2; ++j) {
        const int r = rg + 4 * j;
        if (r < R) orow[r] = acc[j] + bs;
    }
}

// ---------------------------------------------------------------------------
// Last fallback: direct scatter into out
// ---------------------------------------------------------------------------
__global__ void init_out_kernel(const float* __restrict__ bias,
                                float*       __restrict__ out)
{
    const int idx = blockIdx.x * blockDim.x + threadIdx.x;
    if (idx >= B * O * R) return;
    const int o = (idx / R) % O;
    out[idx] = bias[o];
}

__global__ void scatter_direct_kernel(const float* __restrict__ pseudo,
                                      const float* __restrict__ y,
                                      const float* __restrict__ weight,
                                      const int*   __restrict__ ref_idx,
                                      float*       __restrict__ out)
{
    __shared__ float sw[KC * O];
    for (int i = threadIdx.x; i < KC * O; i += blockDim.x)
        sw[i] = weight[i];
    __syncthreads();

    const int lane   = threadIdx.x & 63;
    const int wave   = (blockIdx.x * blockDim.x + threadIdx.x) >> 6;
    const int nwaves = (gridDim.x * blockDim.x) >> 6;

    for (int ev = wave; ev < NEV; ev += nwaves) {
        const int   c    = ev >> 16;
        const float p    = pseudo[ev];
        const float yy   = y[ev];
        const int   ridx = ref_idx[ev];
        const int   b    = ridx / R;
        const int   r    = ridx - b * R;

        const float v    = p * (float)(K - 1);
        const float bot  = floorf(v);
        const float frac = v - bot;
        int i0 = (int)bot;
        int i1 = i0 + 1;
        if (i1 == K) i1 = 0;

        const float w0 = sw[(i0 * C + c) * O + lane];
        const float w1 = sw[(i1 * C + c) * O + lane];
        atomicAdd(&out[((size_t)b * O + lane) * R + r],
                  yy * ((1.0f - frac) * w0 + frac * w1));
    }
}

// ---------------------------------------------------------------------------
extern "C" void kernel_launch(void* const* d_in, const int* in_sizes, int n_in,
                              void* d_out, int out_size, void* d_ws, size_t ws_size,
                              hipStream_t stream)
{
    const float* pseudo  = (const float*)d_in[0];  // [C,E,1]
    const float* y       = (const float*)d_in[1];  // [C,E,1]
    const float* weight  = (const float*)d_in[2];  // [K,C,O]
    const float* bias    = (const float*)d_in[3];  // [O]
    const int*   ref_idx = (const int*)d_in[4];    // [C,E]

    float* out = (float*)d_out;

    const size_t S8_bytes = (size_t)RB * C * 8 * sizeof(float);  // 12.85 MB
    const size_t S_bytes  = (size_t)RB * KC * sizeof(float);     // ~8 MB

    if (ws_size >= S8_bytes) {
        float* S8 = (float*)d_ws;
        hipMemsetAsync(S8, 0, S8_bytes, stream);
        accum_S8_kernel<<<4096, 256, 0, stream>>>(pseudo, y, ref_idx, S8);
        gemm_out_kernel<<<B, 256, 0, stream>>>(S8, weight, bias, out);
    } else if (ws_size >= S_bytes) {
        float* S = (float*)d_ws;
        hipMemsetAsync(S, 0, S_bytes, stream);
        accum_S_kernel<<<2048, 256, 0, stream>>>(pseudo, y, ref_idx, S);
        gemm_out_kernel_flat<<<B, 256, 0, stream>>>(S, weight, bias, out);
    } else {
        const int fin_threads = 256;
        const int fin_blocks = (B * O * R + fin_threads - 1) / fin_threads;
        init_out_kernel<<<fin_blocks, fin_threads, 0, stream>>>(bias, out);
        scatter_direct_kernel<<<4096, 256, 0, stream>>>(
            pseudo, y, weight, ref_idx, out);
    }
}